// Round 4
// baseline (564.596 us; speedup 1.0000x reference)
//
#include <hip/hip_runtime.h>
#include <hip/hip_bf16.h>

// ---------------------------------------------------------------------------
// GNN regression: per timestep t: 3x GCNConv(relu) then edge-MLP head.
//   edge head: relu(concat(x[s],x[d],ea)@We + be) . Wg
//            = relu(u[s] + v[d] + ea@We_ea + be) . Wg,  u=x@We[:128], v=x@We[128:256]
//   GCN agg via CSR-by-dst gather; agg(xW)=agg(x)W; row scale dinv folded in.
// NOTE: reference rebinds W1=W2 after t=0 (`W1 = W2; W1 = W1`).
// R2..R9: edge_mlp 375->62us (LDS-stage, bf16, fp8); MFMA matmuls ~7us.
// R10..R13: fused gather+matmul, 66us/call. R14 balance FAILED (98us).
// R15 depth-8 NEUTRAL. R16 TLP (16 lanes/node, 2x waves): fused_gm ~60us.
// R17: (a) edge_mlp is VALU-bound (58% busy): pack channel math as f32x2 ->
//   v_pk_fma_f32/v_pk_add_f32 (full-rate packed fp32 on CDNA4), consume
//   cvt_pk_f32_fp8's f32x2 output directly. ~48 -> ~28 instrs/edge.
//   (b) fused_gm: remove the hA=hB copy (forced vmcnt(0) drain/iter) via
//   copy-free 2-quad rotation: CONS(A),LQ(A,j),CONS(B),LQ(B,j+4) -> loads
//   stay continuously in flight. Packed de8 decode. FP order preserved.
// ---------------------------------------------------------------------------

typedef __attribute__((ext_vector_type(8))) short bf16x8;
typedef __attribute__((ext_vector_type(4))) float f32x4;
typedef __attribute__((ext_vector_type(2))) float f32x2;

__device__ __forceinline__ unsigned short f2bf(float f) {
    union { float f; unsigned int u; } v; v.f = f;
    unsigned int r = v.u + 0x7fffu + ((v.u >> 16) & 1u);  // RNE
    return (unsigned short)(r >> 16);
}
__device__ __forceinline__ unsigned int pk2bf(float lo, float hi) {
    return (unsigned int)f2bf(lo) | ((unsigned int)f2bf(hi) << 16);
}
// fp8 e4m3 (OCP on gfx950) via HW converts
__device__ __forceinline__ unsigned char f2fp8(float f) {
    return (unsigned char)(__builtin_amdgcn_cvt_pk_fp8_f32(f, f, 0, false) & 0xff);
}
__device__ __forceinline__ void fp8x4(unsigned int u, float* o) {
    f32x2 lo = __builtin_amdgcn_cvt_pk_f32_fp8(u, false);
    f32x2 hi = __builtin_amdgcn_cvt_pk_f32_fp8(u, true);
    o[0] = lo[0]; o[1] = lo[1]; o[2] = hi[0]; o[3] = hi[1];
}
__device__ __forceinline__ f32x2 max0_2(f32x2 v) {
#if __has_builtin(__builtin_elementwise_max)
    return __builtin_elementwise_max(v, (f32x2){0.f, 0.f});
#else
    return (f32x2){fmaxf(v[0], 0.f), fmaxf(v[1], 0.f)};
#endif
}

__global__ void to_bf16(const float* __restrict__ in, unsigned short* __restrict__ out, int n4)
{
    int i = blockIdx.x * 256 + threadIdx.x;
    if (i < n4) {
        float4 v = ((const float4*)in)[i];
        ushort4 o;
        o.x = f2bf(v.x); o.y = f2bf(v.y); o.z = f2bf(v.z); o.w = f2bf(v.w);
        ((ushort4*)out)[i] = o;
    }
}

// Transpose weight blocks -> bf16 Wt[c*128+k], once per launch.
// y: 0:W1->T1  1:W2->T2  2:W3->T3  3:We_u->Tuv[0]  4:We_v->Tuv[128^2]
//    5:W2->Tuv[256*128]  (boundary fused kernel's extra cols = next-t conv1)
__global__ void transpose_w(
    const float* __restrict__ W1, const float* __restrict__ W2,
    const float* __restrict__ W3, const float* __restrict__ We,
    unsigned short* __restrict__ T1, unsigned short* __restrict__ T2,
    unsigned short* __restrict__ T3, unsigned short* __restrict__ Tuv)
{
    const float* src; unsigned short* dst;
    switch (blockIdx.y) {
        case 0:  src = W1;             dst = T1;               break;
        case 1:  src = W2;             dst = T2;               break;
        case 2:  src = W3;             dst = T3;               break;
        case 3:  src = We;             dst = Tuv;              break;
        case 4:  src = We + 128 * 128; dst = Tuv + 128 * 128;  break;
        default: src = W2;             dst = Tuv + 256 * 128;  break;
    }
    for (int i = blockIdx.x * 256 + threadIdx.x; i < 128 * 128; i += 256 * gridDim.x) {
        int k = i >> 7, c = i & 127;
        dst[c * 128 + k] = f2bf(src[i]);
    }
}

// ---------------- standalone MFMA matmul (t=0 conv1 only) -------------------
__global__ __launch_bounds__(256) void mfma_matmul(
    const unsigned short* __restrict__ X, const unsigned short* __restrict__ Wt,
    unsigned char* __restrict__ out, const float* __restrict__ scale, int n_rows)
{
    const int wave = threadIdx.x >> 6;
    const int lane = threadIdx.x & 63;
    const int m = lane & 15;
    const int q = lane >> 4;
    const int r = blockIdx.x * 64 + wave * 16 + m;
    const bool rv = r < n_rows;

    f32x4 acc[8];
    #pragma unroll
    for (int i = 0; i < 8; ++i) acc[i] = (f32x4){0.f, 0.f, 0.f, 0.f};

    #pragma unroll
    for (int k0 = 0; k0 < 128; k0 += 32) {
        bf16x8 a = {};
        if (rv) a = *(const bf16x8*)(X + (size_t)r * 128 + k0 + q * 8);
        #pragma unroll
        for (int ct = 0; ct < 8; ++ct) {
            bf16x8 b = *(const bf16x8*)(Wt + (ct * 16 + m) * 128 + k0 + q * 8);
            acc[ct] = __builtin_amdgcn_mfma_f32_16x16x32_bf16(a, b, acc[ct], 0, 0, 0);
        }
    }

    #pragma unroll
    for (int reg = 0; reg < 4; ++reg) {
        int gr = blockIdx.x * 64 + wave * 16 + q * 4 + reg;
        if (gr >= n_rows) continue;
        float s = scale[gr];
        #pragma unroll
        for (int ct = 0; ct < 8; ++ct)
            out[(size_t)gr * 128 + ct * 16 + m] = f2fp8(acc[ct][reg] * s);
    }
}

// ---------------- FUSED gather + matmul -------------------------------------
// R16/R17: 16 nodes/block, 16 lanes/node x 8 fp8-ch (uint2 loads). Per-GROUP
// idx staging into LDS (no block barrier; rows are the only vmcnt items).
// Copy-free 2-quad rotation keeps 4-8 rows continuously in flight (no
// per-iter vmcnt(0) drain). Packed f32x2 accumulate. Phase B: MFMA vs Wt.
#define FPAD 136
#define GN 16
#define ICAP 64
#define ISTR 72   // idx row stride (dwords)
__global__ __launch_bounds__(256, 8) void fused_gm(
    const unsigned char* __restrict__ hs_in, const int* __restrict__ csr_src,
    const int* __restrict__ offs, const int* __restrict__ counts,
    const float* __restrict__ dinv, const float* __restrict__ bias,
    const unsigned short* __restrict__ Wt, int ncols, int uvcols,
    unsigned char* __restrict__ buv, unsigned char* __restrict__ bh, int n)
{
    __shared__ unsigned short xs[GN * FPAD];   // 4352 B
    __shared__ int idxl[GN * ISTR];            // 4608 B
    const int tid = threadIdx.x;
    const int row = tid >> 4;                  // node-in-block 0..15
    const int node = blockIdx.x * GN + row;
    const int lg = tid & 15;                   // lane-in-group
    const int c8 = lg * 8;                     // fp8-channel base

    if (node < n) {
        const int off = offs[node];
        const int cnt = counts[node];
        const int cap = min(cnt, ICAP);

        // group-local idx stage: 16 lanes, coalesced stride-1 global reads.
        for (int j = lg; j < cap; j += 16)
            idxl[row * ISTR + j] = csr_src[off + j];

        // self row: issue load now, consume while first quads in flight
        const uint2 sv = *(const uint2*)(hs_in + (size_t)node * 128 + c8);

        f32x2 a01 = {0.f, 0.f}, a23 = {0.f, 0.f}, a45 = {0.f, 0.f}, a67 = {0.f, 0.f};
        auto de8 = [&](uint2 v) {
            a01 += __builtin_amdgcn_cvt_pk_f32_fp8(v.x, false);
            a23 += __builtin_amdgcn_cvt_pk_f32_fp8(v.x, true);
            a45 += __builtin_amdgcn_cvt_pk_f32_fp8(v.y, false);
            a67 += __builtin_amdgcn_cvt_pk_f32_fp8(v.y, true);
        };
        uint2 A[4], B[4];
        auto LQ = [&](uint2* Q, int jb) {
            #pragma unroll
            for (int q = 0; q < 4; ++q)
                Q[q] = *(const uint2*)(hs_in + (size_t)idxl[row * ISTR + jb + q] * 128 + c8);
        };
        auto CONS = [&](uint2* Q) {
            #pragma unroll
            for (int q = 0; q < 4; ++q) de8(Q[q]);
        };

        int j = 0;
        if (cap >= 8) {
            LQ(A, 0); LQ(B, 4);
            de8(sv);                           // overlap with A/B latency
            j = 8;
            for (; j + 8 <= cap; j += 8) {
                CONS(A); LQ(A, j);             // B (+new A) stay in flight
                CONS(B); LQ(B, j + 4);
            }
            CONS(A); CONS(B);
        } else if (cap >= 4) {
            LQ(A, 0);
            de8(sv);
            CONS(A);
            j = 4;
        } else {
            de8(sv);
        }
        if (j + 4 <= cap) {                    // tail quad
            LQ(A, j); CONS(A); j += 4;
        }
        for (; j < cap; ++j)
            de8(*(const uint2*)(hs_in + (size_t)idxl[row * ISTR + j] * 128 + c8));
        for (; j < cnt; ++j)   // >ICAP overflow: effectively never (P~1e-20)
            de8(*(const uint2*)(hs_in + (size_t)csr_src[off + j] * 128 + c8));

        const float dn = dinv[node];
        const float4 b0 = *(const float4*)(bias + c8);
        const float4 b1v = *(const float4*)(bias + c8 + 4);
        float r0 = fmaxf(fmaf(a01[0], dn, b0.x), 0.f);
        float r1 = fmaxf(fmaf(a01[1], dn, b0.y), 0.f);
        float r2 = fmaxf(fmaf(a23[0], dn, b0.z), 0.f);
        float r3 = fmaxf(fmaf(a23[1], dn, b0.w), 0.f);
        float r4 = fmaxf(fmaf(a45[0], dn, b1v.x), 0.f);
        float r5 = fmaxf(fmaf(a45[1], dn, b1v.y), 0.f);
        float r6 = fmaxf(fmaf(a67[0], dn, b1v.z), 0.f);
        float r7 = fmaxf(fmaf(a67[1], dn, b1v.w), 0.f);
        uint4 w;
        w.x = pk2bf(r0, r1); w.y = pk2bf(r2, r3);
        w.z = pk2bf(r4, r5); w.w = pk2bf(r6, r7);
        *(uint4*)&xs[row * FPAD + c8] = w;     // byte off = row*272 + lg*16, 16B-aligned
    }
    __syncthreads();

    // ---- Phase B: MFMA x(LDS) @ Wt -> fp8 outputs --------------------------
    // 16-row tile; 4 waves each take nct/4 column tiles (nct in {8,16,24}).
    const int wave = tid >> 6;
    const int lane = tid & 63;
    const int m = lane & 15;
    const int q = lane >> 4;
    const int nct = ncols >> 4;
    const int per = nct >> 2;
    const int ct0 = wave * per;

    for (int ci = 0; ci < per; ++ci) {
        const int ct = ct0 + ci;
        f32x4 acc = (f32x4){0.f, 0.f, 0.f, 0.f};
        #pragma unroll
        for (int k0 = 0; k0 < 128; k0 += 32) {
            bf16x8 a = *(const bf16x8*)&xs[m * FPAD + k0 + q * 8];
            bf16x8 b = *(const bf16x8*)(Wt + (size_t)(ct * 16 + m) * 128 + k0 + q * 8);
            acc = __builtin_amdgcn_mfma_f32_16x16x32_bf16(a, b, acc, 0, 0, 0);
        }
        const int col = ct * 16 + m;
        #pragma unroll
        for (int reg = 0; reg < 4; ++reg) {
            int nd = blockIdx.x * GN + q * 4 + reg;
            if (nd >= n) continue;
            if (col < uvcols)
                buv[(size_t)nd * 256 + col] = f2fp8(acc[reg]);
            else
                bh[(size_t)nd * 128 + col - uvcols] = f2fp8(acc[reg] * dinv[nd]);
        }
    }
}

// acc += sum_e relu(u[src_e] + v[dst_e] + ea_e@We_ea + be) . Wg   (uv fp8)
// R17: packed f32x2 math (v_pk_fma_f32/v_pk_add_f32) -> ~28 instr/edge-pair.
#define EM_CHUNK 256
__global__ __launch_bounds__(256) void edge_mlp(
    const unsigned char* __restrict__ uv, const int* __restrict__ src,
    const int* __restrict__ dst, const float* __restrict__ ea,
    const float* __restrict__ We_e, const float* __restrict__ be,
    const float* __restrict__ Wg, float* __restrict__ acc, int E)
{
    const int tid  = threadIdx.x;
    const int lane = tid & 31;
    const int g    = tid >> 5;
    const int c4   = lane * 4;

    __shared__ float eas[EM_CHUNK * 7];
    __shared__ int   ss[EM_CHUNK];
    __shared__ int   ds[EM_CHUNK];
    __shared__ float red[256];

    f32x2 wlo[7], whi[7];
    #pragma unroll
    for (int i = 0; i < 7; ++i) {
        float4 wv = *(const float4*)(We_e + i * 128 + c4);
        wlo[i] = (f32x2){wv.x, wv.y};
        whi[i] = (f32x2){wv.z, wv.w};
    }
    const float4 bev = *(const float4*)(be + c4);
    const f32x2 be01 = (f32x2){bev.x, bev.y};
    const f32x2 be23 = (f32x2){bev.z, bev.w};
    const float4 wg4 = *(const float4*)(Wg + c4);

    f32x2 part01 = {0.f, 0.f}, part23 = {0.f, 0.f};

    for (int base = blockIdx.x * EM_CHUNK; base < E; base += gridDim.x * EM_CHUNK) {
        const int nch = min(EM_CHUNK, E - base);
        for (int i = tid; i < nch * 7; i += 256)
            eas[i] = ea[(size_t)base * 7 + i];
        for (int i = tid; i < nch; i += 256) {
            ss[i] = src[base + i];
            ds[i] = dst[base + i];
        }
        __syncthreads();

        auto ev = [&](int j) {
            unsigned int us = *(const unsigned int*)(uv + (size_t)ss[j] * 256 + c4);
            unsigned int vs = *(const unsigned int*)(uv + (size_t)ds[j] * 256 + 128 + c4);
            f32x2 u01 = __builtin_amdgcn_cvt_pk_f32_fp8(us, false);
            f32x2 u23 = __builtin_amdgcn_cvt_pk_f32_fp8(us, true);
            f32x2 v01 = __builtin_amdgcn_cvt_pk_f32_fp8(vs, false);
            f32x2 v23 = __builtin_amdgcn_cvt_pk_f32_fp8(vs, true);
            f32x2 val01 = u01 + v01 + be01;
            f32x2 val23 = u23 + v23 + be23;
            const float* eav = &eas[j * 7];
            #pragma unroll
            for (int i = 0; i < 7; ++i) {
                f32x2 e2 = (f32x2){eav[i], eav[i]};
                val01 += e2 * wlo[i];          // v_pk_fma_f32
                val23 += e2 * whi[i];
            }
            part01 += max0_2(val01);
            part23 += max0_2(val23);
        };

        int j = g;
        for (; j + 32 <= nch; j += 32) {
            ev(j); ev(j + 8); ev(j + 16); ev(j + 24);
        }
        for (; j < nch; j += 8)
            ev(j);
        __syncthreads();
    }

    float p = part01[0] * wg4.x + part01[1] * wg4.y + part23[0] * wg4.z + part23[1] * wg4.w;
    red[tid] = p;
    __syncthreads();
    for (int s = 128; s > 0; s >>= 1) {
        if (tid < s) red[tid] += red[tid + s];
        __syncthreads();
    }
    if (tid == 0) atomicAdd(acc, red[0]);
}

// ---------------- CSR build ----------------
__global__ void count_edges(const int* __restrict__ dst, int* __restrict__ counts, int E)
{
    int e = blockIdx.x * 256 + threadIdx.x;
    if (e < E) atomicAdd(&counts[dst[e]], 1);
}

__global__ void compute_dinv(const int* __restrict__ counts, float* __restrict__ dinv, int n)
{
    int i = blockIdx.x * 256 + threadIdx.x;
    if (i < n) dinv[i] = rsqrtf((float)counts[i] + 1.0f);
}

__global__ void scan1(const int* __restrict__ counts, int* __restrict__ scanned,
                      int* __restrict__ btot, int n)
{
    __shared__ int sh[256];
    int i = blockIdx.x * 256 + threadIdx.x;
    int v = (i < n) ? counts[i] : 0;
    sh[threadIdx.x] = v;
    __syncthreads();
    for (int off = 1; off < 256; off <<= 1) {
        int t = (threadIdx.x >= off) ? sh[threadIdx.x - off] : 0;
        __syncthreads();
        sh[threadIdx.x] += t;
        __syncthreads();
    }
    if (i < n) scanned[i] = sh[threadIdx.x] - v;  // exclusive
    if (threadIdx.x == 255) btot[blockIdx.x] = sh[255];
}

__global__ void scan2(int* __restrict__ btot, int nb)
{
    __shared__ int sh[256];
    int v = (threadIdx.x < nb) ? btot[threadIdx.x] : 0;
    sh[threadIdx.x] = v;
    __syncthreads();
    for (int off = 1; off < 256; off <<= 1) {
        int t = (threadIdx.x >= off) ? sh[threadIdx.x - off] : 0;
        __syncthreads();
        sh[threadIdx.x] += t;
        __syncthreads();
    }
    if (threadIdx.x < nb) btot[threadIdx.x] = sh[threadIdx.x] - v;  // exclusive
}

__global__ void scan3(const int* __restrict__ scanned, const int* __restrict__ btot,
                      int* __restrict__ offs, int* __restrict__ cursor, int n)
{
    int i = blockIdx.x * 256 + threadIdx.x;
    if (i < n) {
        int o = scanned[i] + btot[blockIdx.x];
        offs[i] = o;
        cursor[i] = o;
    }
}

__global__ void fill_csr(const int* __restrict__ src, const int* __restrict__ dst,
                         int* __restrict__ cursor, int* __restrict__ csr_src, int E)
{
    int e = blockIdx.x * 256 + threadIdx.x;
    if (e < E) {
        int slot = atomicAdd(&cursor[dst[e]], 1);
        csr_src[slot] = src[e];
    }
}

__global__ void write_out(const float* __restrict__ acc, const float* __restrict__ bg,
                          float* __restrict__ out, float invE, int T)
{
    int t = threadIdx.x;
    if (t < T) out[t] = acc[t] * invE + bg[0];
}

// ---------------------------------------------------------------------------

extern "C" void kernel_launch(void* const* d_in, const int* in_sizes, int n_in,
                              void* d_out, int out_size, void* d_ws, size_t ws_size,
                              hipStream_t stream)
{
    const float* x   = (const float*)d_in[0];
    const int*  eidx = (const int*)d_in[1];
    const float* ea  = (const float*)d_in[2];
    const float* W1  = (const float*)d_in[3];
    const float* b1  = (const float*)d_in[4];
    const float* W2  = (const float*)d_in[5];
    const float* b2  = (const float*)d_in[6];
    const float* W3  = (const float*)d_in[7];
    const float* b3  = (const float*)d_in[8];
    const float* We  = (const float*)d_in[9];
    const float* be  = (const float*)d_in[10];
    const float* Wg  = (const float*)d_in[11];
    const float* bg  = (const float*)d_in[12];

    const int N = in_sizes[0] / 128;
    const int E = in_sizes[1] / 2;
    const int T = in_sizes[2] / (E * 7);
    const int* src = eidx;
    const int* dst = eidx + E;

    char* wsp = (char*)d_ws;
    auto alloc = [&](size_t bytes) -> char* {
        char* p = wsp;
        wsp += (bytes + 255) / 256 * 256;
        return p;
    };
    int*   counts  = (int*)alloc((size_t)N * 4);
    int*   offs    = (int*)alloc((size_t)N * 4);
    int*   cursor  = (int*)alloc((size_t)N * 4);
    int*   scanned = (int*)alloc((size_t)N * 4);
    int*   btot    = (int*)alloc(1024);
    int*   csr_src = (int*)alloc((size_t)E * 4);
    float* dinv    = (float*)alloc((size_t)N * 4);
    float* acc     = (float*)alloc(256);
    unsigned short* X0  = (unsigned short*)alloc((size_t)N * 128 * 2);  // x bf16
    unsigned char*  Bh0 = (unsigned char*)alloc((size_t)N * 128);       // hs fp8 (dbuf)
    unsigned char*  Bh1 = (unsigned char*)alloc((size_t)N * 128);
    unsigned char*  Buv = (unsigned char*)alloc((size_t)N * 256);       // uv fp8
    unsigned short* T1  = (unsigned short*)alloc(128 * 128 * 2);        // W^T bf16
    unsigned short* T2  = (unsigned short*)alloc(128 * 128 * 2);
    unsigned short* T3  = (unsigned short*)alloc(128 * 128 * 2);
    unsigned short* Tuv = (unsigned short*)alloc(384 * 128 * 2);        // [We_u|We_v|W2]^T

    hipMemsetAsync(counts, 0, (size_t)N * 4, stream);
    hipMemsetAsync(acc, 0, (size_t)T * 4, stream);

    to_bf16<<<(N * 128 / 4 + 255) / 256, 256, 0, stream>>>(x, X0, N * 128 / 4);
    transpose_w<<<dim3(8, 6), 256, 0, stream>>>(W1, W2, W3, We, T1, T2, T3, Tuv);

    count_edges<<<(E + 255) / 256, 256, 0, stream>>>(dst, counts, E);
    compute_dinv<<<(N + 255) / 256, 256, 0, stream>>>(counts, dinv, N);
    const int nb = (N + 255) / 256;
    scan1<<<nb, 256, 0, stream>>>(counts, scanned, btot, N);
    scan2<<<1, 256, 0, stream>>>(btot, nb);
    scan3<<<nb, 256, 0, stream>>>(scanned, btot, offs, cursor, N);
    fill_csr<<<(E + 255) / 256, 256, 0, stream>>>(src, dst, cursor, csr_src, E);

    const int mmb = (N + 63) / 64;
    const int fgb = (N + GN - 1) / GN;
    const int emb = (E + EM_CHUNK - 1) / EM_CHUNK;

    unsigned char* hcur = Bh0;
    unsigned char* hnxt = Bh1;

    for (int t = 0; t < T; ++t) {
        if (t == 0) {
            // hs1 = (x @ W1) * dinv   (only timestep that uses W1)
            mfma_matmul<<<mmb, 256, 0, stream>>>(X0, T1, hcur, dinv, N);
        }
        // x2 = relu(agg(hs1)*dinv + b1); hs2 = (x2 @ W2) * dinv
        fused_gm<<<fgb, 256, 0, stream>>>(hcur, csr_src, offs, counts, dinv, b1,
                                          T2, 128, 0, Buv, hnxt, N);
        { unsigned char* tmp = hcur; hcur = hnxt; hnxt = tmp; }
        // x3' = relu(agg(hs2)*dinv + b2); hs3 = (x3' @ W3) * dinv
        fused_gm<<<fgb, 256, 0, stream>>>(hcur, csr_src, offs, counts, dinv, b2,
                                          T3, 128, 0, Buv, hnxt, N);
        { unsigned char* tmp = hcur; hcur = hnxt; hnxt = tmp; }
        // x3 = relu(agg(hs3)*dinv + b3); uv = x3 @ [We_u|We_v];
        // if not last timestep also hs1' = (x3 @ W2) * dinv  (W1:=W2 rebind)
        bool last = (t == T - 1);
        fused_gm<<<fgb, 256, 0, stream>>>(hcur, csr_src, offs, counts, dinv, b3,
                                          Tuv, last ? 256 : 384, 256, Buv, hnxt, N);
        if (!last) { unsigned char* tmp = hcur; hcur = hnxt; hnxt = tmp; }

        edge_mlp<<<emb, 256, 0, stream>>>(Buv, src, dst, ea + (size_t)t * E * 7,
                                          We + 256 * 128, be, Wg, acc + t, E);
    }
    write_out<<<1, 64, 0, stream>>>(acc, bg, (float*)d_out, 1.0f / (float)E, T);
}

// Round 5
// 541.991 us; speedup vs baseline: 1.0417x; 1.0417x over previous
//
#include <hip/hip_runtime.h>
#include <hip/hip_bf16.h>

// ---------------------------------------------------------------------------
// GNN regression: per timestep t: 3x GCNConv(relu) then edge-MLP head.
//   edge head: relu(concat(x[s],x[d],ea)@We + be) . Wg
//            = relu(u[s] + v[d] + ea@We_ea + be) . Wg,  u=x@We[:128], v=x@We[128:256]
//   GCN agg via CSR-by-dst gather; agg(xW)=agg(x)W; row scale dinv folded in.
// NOTE: reference rebinds W1=W2 after t=0 (`W1 = W2; W1 = W1`).
// R10..R17 history: fused gather+matmul ~58-66us/call. Balance (R14) FAILED,
//   depth-8 ILP (R15) NEUTRAL, 2x TLP (R16) small win, packed f32x2 (R17):
//   VALUBusy 58->43 but dur flat -> gather kernels are memory-service-bound
//   at ~1.5 TB/s logical; scheduling levers exhausted.
// R18 (this round), structural:
//   (a) fill_csr was 64us, WRITE_SIZE=52MB: 800k scattered 4B stores, each
//       dirtying a 64B line. Fix: rank[e]=atomicAdd in count pass (coalesced
//       write, no atomics in fill), then XCD-chunked fill: blocks with
//       blockIdx%8==g write only dst-range g (contiguous csr_src slice ->
//       stays in that XCD's L2; writeback 52MB->~3.2MB). Heuristic only
//       affects perf, never correctness.
//   (b) E(t) and Fa(t+1) both depend only on Fc(t) -> co-dispatch as ONE
//       kernel (role by blockIdx in chunks of 8 to respect XCD round-robin;
//       parity would segregate roles onto disjoint XCDs). Both halves are
//       latency-bound (<45% on every pipe) -> waves interleave, 120us->~75.
// ---------------------------------------------------------------------------

typedef __attribute__((ext_vector_type(8))) short bf16x8;
typedef __attribute__((ext_vector_type(4))) float f32x4;
typedef __attribute__((ext_vector_type(2))) float f32x2;

__device__ __forceinline__ unsigned short f2bf(float f) {
    union { float f; unsigned int u; } v; v.f = f;
    unsigned int r = v.u + 0x7fffu + ((v.u >> 16) & 1u);  // RNE
    return (unsigned short)(r >> 16);
}
__device__ __forceinline__ unsigned int pk2bf(float lo, float hi) {
    return (unsigned int)f2bf(lo) | ((unsigned int)f2bf(hi) << 16);
}
// fp8 e4m3 (OCP on gfx950) via HW converts
__device__ __forceinline__ unsigned char f2fp8(float f) {
    return (unsigned char)(__builtin_amdgcn_cvt_pk_fp8_f32(f, f, 0, false) & 0xff);
}
__device__ __forceinline__ f32x2 max0_2(f32x2 v) {
#if __has_builtin(__builtin_elementwise_max)
    return __builtin_elementwise_max(v, (f32x2){0.f, 0.f});
#else
    return (f32x2){fmaxf(v[0], 0.f), fmaxf(v[1], 0.f)};
#endif
}

__global__ void to_bf16(const float* __restrict__ in, unsigned short* __restrict__ out, int n4)
{
    int i = blockIdx.x * 256 + threadIdx.x;
    if (i < n4) {
        float4 v = ((const float4*)in)[i];
        ushort4 o;
        o.x = f2bf(v.x); o.y = f2bf(v.y); o.z = f2bf(v.z); o.w = f2bf(v.w);
        ((ushort4*)out)[i] = o;
    }
}

// Transpose weight blocks -> bf16 Wt[c*128+k], once per launch.
__global__ void transpose_w(
    const float* __restrict__ W1, const float* __restrict__ W2,
    const float* __restrict__ W3, const float* __restrict__ We,
    unsigned short* __restrict__ T1, unsigned short* __restrict__ T2,
    unsigned short* __restrict__ T3, unsigned short* __restrict__ Tuv)
{
    const float* src; unsigned short* dst;
    switch (blockIdx.y) {
        case 0:  src = W1;             dst = T1;               break;
        case 1:  src = W2;             dst = T2;               break;
        case 2:  src = W3;             dst = T3;               break;
        case 3:  src = We;             dst = Tuv;              break;
        case 4:  src = We + 128 * 128; dst = Tuv + 128 * 128;  break;
        default: src = W2;             dst = Tuv + 256 * 128;  break;
    }
    for (int i = blockIdx.x * 256 + threadIdx.x; i < 128 * 128; i += 256 * gridDim.x) {
        int k = i >> 7, c = i & 127;
        dst[c * 128 + k] = f2bf(src[i]);
    }
}

// ---------------- standalone MFMA matmul (t=0 conv1 only) -------------------
__global__ __launch_bounds__(256) void mfma_matmul(
    const unsigned short* __restrict__ X, const unsigned short* __restrict__ Wt,
    unsigned char* __restrict__ out, const float* __restrict__ scale, int n_rows)
{
    const int wave = threadIdx.x >> 6;
    const int lane = threadIdx.x & 63;
    const int m = lane & 15;
    const int q = lane >> 4;
    const int r = blockIdx.x * 64 + wave * 16 + m;
    const bool rv = r < n_rows;

    f32x4 acc[8];
    #pragma unroll
    for (int i = 0; i < 8; ++i) acc[i] = (f32x4){0.f, 0.f, 0.f, 0.f};

    #pragma unroll
    for (int k0 = 0; k0 < 128; k0 += 32) {
        bf16x8 a = {};
        if (rv) a = *(const bf16x8*)(X + (size_t)r * 128 + k0 + q * 8);
        #pragma unroll
        for (int ct = 0; ct < 8; ++ct) {
            bf16x8 b = *(const bf16x8*)(Wt + (ct * 16 + m) * 128 + k0 + q * 8);
            acc[ct] = __builtin_amdgcn_mfma_f32_16x16x32_bf16(a, b, acc[ct], 0, 0, 0);
        }
    }

    #pragma unroll
    for (int reg = 0; reg < 4; ++reg) {
        int gr = blockIdx.x * 64 + wave * 16 + q * 4 + reg;
        if (gr >= n_rows) continue;
        float s = scale[gr];
        #pragma unroll
        for (int ct = 0; ct < 8; ++ct)
            out[(size_t)gr * 128 + ct * 16 + m] = f2fp8(acc[ct][reg] * s);
    }
}

// ---------------- FUSED gather + matmul body --------------------------------
// 16 nodes/block, 16 lanes/node x 8 fp8-ch (uint2 loads). Per-GROUP idx
// staging into LDS; copy-free 2-quad rotation; packed f32x2 accumulate.
#define FPAD 136
#define GN 16
#define ICAP 64
#define ISTR 72
#define FUSED_LDS (GN * FPAD * 2 + GN * ISTR * 4)   // 8960
#define EDGE_LDS  10240
#define EM_CHUNK 256

__device__ __forceinline__ void fused_body(
    int bx, char* smem,
    const unsigned char* __restrict__ hs_in, const int* __restrict__ csr_src,
    const int* __restrict__ offs, const int* __restrict__ counts,
    const float* __restrict__ dinv, const float* __restrict__ bias,
    const unsigned short* __restrict__ Wt, int ncols, int uvcols,
    unsigned char* __restrict__ buv, unsigned char* __restrict__ bh, int n)
{
    unsigned short* xs = (unsigned short*)smem;        // GN*FPAD shorts
    int* idxl = (int*)(smem + GN * FPAD * 2);          // GN*ISTR ints
    const int tid = threadIdx.x;
    const int row = tid >> 4;                  // node-in-block 0..15
    const int node = bx * GN + row;
    const int lg = tid & 15;                   // lane-in-group
    const int c8 = lg * 8;                     // fp8-channel base

    if (node < n) {
        const int off = offs[node];
        const int cnt = counts[node];
        const int cap = min(cnt, ICAP);

        for (int j = lg; j < cap; j += 16)
            idxl[row * ISTR + j] = csr_src[off + j];

        const uint2 sv = *(const uint2*)(hs_in + (size_t)node * 128 + c8);

        f32x2 a01 = {0.f, 0.f}, a23 = {0.f, 0.f}, a45 = {0.f, 0.f}, a67 = {0.f, 0.f};
        auto de8 = [&](uint2 v) {
            a01 += __builtin_amdgcn_cvt_pk_f32_fp8(v.x, false);
            a23 += __builtin_amdgcn_cvt_pk_f32_fp8(v.x, true);
            a45 += __builtin_amdgcn_cvt_pk_f32_fp8(v.y, false);
            a67 += __builtin_amdgcn_cvt_pk_f32_fp8(v.y, true);
        };
        uint2 A[4], B[4];
        auto LQ = [&](uint2* Q, int jb) {
            #pragma unroll
            for (int q = 0; q < 4; ++q)
                Q[q] = *(const uint2*)(hs_in + (size_t)idxl[row * ISTR + jb + q] * 128 + c8);
        };
        auto CONS = [&](uint2* Q) {
            #pragma unroll
            for (int q = 0; q < 4; ++q) de8(Q[q]);
        };

        int j = 0;
        if (cap >= 8) {
            LQ(A, 0); LQ(B, 4);
            de8(sv);
            j = 8;
            for (; j + 8 <= cap; j += 8) {
                CONS(A); LQ(A, j);
                CONS(B); LQ(B, j + 4);
            }
            CONS(A); CONS(B);
        } else if (cap >= 4) {
            LQ(A, 0);
            de8(sv);
            CONS(A);
            j = 4;
        } else {
            de8(sv);
        }
        if (j + 4 <= cap) {
            LQ(A, j); CONS(A); j += 4;
        }
        for (; j < cap; ++j)
            de8(*(const uint2*)(hs_in + (size_t)idxl[row * ISTR + j] * 128 + c8));
        for (; j < cnt; ++j)   // >ICAP overflow: effectively never
            de8(*(const uint2*)(hs_in + (size_t)csr_src[off + j] * 128 + c8));

        const float dn = dinv[node];
        const float4 b0 = *(const float4*)(bias + c8);
        const float4 b1v = *(const float4*)(bias + c8 + 4);
        float r0 = fmaxf(fmaf(a01[0], dn, b0.x), 0.f);
        float r1 = fmaxf(fmaf(a01[1], dn, b0.y), 0.f);
        float r2 = fmaxf(fmaf(a23[0], dn, b0.z), 0.f);
        float r3 = fmaxf(fmaf(a23[1], dn, b0.w), 0.f);
        float r4 = fmaxf(fmaf(a45[0], dn, b1v.x), 0.f);
        float r5 = fmaxf(fmaf(a45[1], dn, b1v.y), 0.f);
        float r6 = fmaxf(fmaf(a67[0], dn, b1v.z), 0.f);
        float r7 = fmaxf(fmaf(a67[1], dn, b1v.w), 0.f);
        uint4 w;
        w.x = pk2bf(r0, r1); w.y = pk2bf(r2, r3);
        w.z = pk2bf(r4, r5); w.w = pk2bf(r6, r7);
        *(uint4*)&xs[row * FPAD + c8] = w;
    }
    __syncthreads();

    // ---- Phase B: MFMA x(LDS) @ Wt -> fp8 outputs --------------------------
    const int wave = tid >> 6;
    const int lane = tid & 63;
    const int m = lane & 15;
    const int q = lane >> 4;
    const int nct = ncols >> 4;
    const int per = nct >> 2;
    const int ct0 = wave * per;

    for (int ci = 0; ci < per; ++ci) {
        const int ct = ct0 + ci;
        f32x4 acc = (f32x4){0.f, 0.f, 0.f, 0.f};
        #pragma unroll
        for (int k0 = 0; k0 < 128; k0 += 32) {
            bf16x8 a = *(const bf16x8*)&xs[m * FPAD + k0 + q * 8];
            bf16x8 b = *(const bf16x8*)(Wt + (size_t)(ct * 16 + m) * 128 + k0 + q * 8);
            acc = __builtin_amdgcn_mfma_f32_16x16x32_bf16(a, b, acc, 0, 0, 0);
        }
        const int col = ct * 16 + m;
        #pragma unroll
        for (int reg = 0; reg < 4; ++reg) {
            int nd = bx * GN + q * 4 + reg;
            if (nd >= n) continue;
            if (col < uvcols)
                buv[(size_t)nd * 256 + col] = f2fp8(acc[reg]);
            else
                bh[(size_t)nd * 128 + col - uvcols] = f2fp8(acc[reg] * dinv[nd]);
        }
    }
}

// ---------------- edge-MLP body ---------------------------------------------
__device__ __forceinline__ void edge_body(
    int bx, int nbx, char* smem,
    const unsigned char* __restrict__ uv, const int* __restrict__ src,
    const int* __restrict__ dst, const float* __restrict__ ea,
    const float* __restrict__ We_e, const float* __restrict__ be,
    const float* __restrict__ Wg, float* __restrict__ acc, int E)
{
    float* eas = (float*)smem;                 // EM_CHUNK*7 floats
    int*   ss  = (int*)(smem + 7168);
    int*   ds  = (int*)(smem + 8192);
    float* red = (float*)(smem + 9216);

    const int tid  = threadIdx.x;
    const int lane = tid & 31;
    const int g    = tid >> 5;
    const int c4   = lane * 4;

    f32x2 wlo[7], whi[7];
    #pragma unroll
    for (int i = 0; i < 7; ++i) {
        float4 wv = *(const float4*)(We_e + i * 128 + c4);
        wlo[i] = (f32x2){wv.x, wv.y};
        whi[i] = (f32x2){wv.z, wv.w};
    }
    const float4 bev = *(const float4*)(be + c4);
    const f32x2 be01 = (f32x2){bev.x, bev.y};
    const f32x2 be23 = (f32x2){bev.z, bev.w};
    const float4 wg4 = *(const float4*)(Wg + c4);

    f32x2 part01 = {0.f, 0.f}, part23 = {0.f, 0.f};

    for (int base = bx * EM_CHUNK; base < E; base += nbx * EM_CHUNK) {
        const int nch = min(EM_CHUNK, E - base);
        for (int i = tid; i < nch * 7; i += 256)
            eas[i] = ea[(size_t)base * 7 + i];
        for (int i = tid; i < nch; i += 256) {
            ss[i] = src[base + i];
            ds[i] = dst[base + i];
        }
        __syncthreads();

        auto ev = [&](int j) {
            unsigned int us = *(const unsigned int*)(uv + (size_t)ss[j] * 256 + c4);
            unsigned int vs = *(const unsigned int*)(uv + (size_t)ds[j] * 256 + 128 + c4);
            f32x2 u01 = __builtin_amdgcn_cvt_pk_f32_fp8(us, false);
            f32x2 u23 = __builtin_amdgcn_cvt_pk_f32_fp8(us, true);
            f32x2 v01 = __builtin_amdgcn_cvt_pk_f32_fp8(vs, false);
            f32x2 v23 = __builtin_amdgcn_cvt_pk_f32_fp8(vs, true);
            f32x2 val01 = u01 + v01 + be01;
            f32x2 val23 = u23 + v23 + be23;
            const float* eav = &eas[j * 7];
            #pragma unroll
            for (int i = 0; i < 7; ++i) {
                f32x2 e2 = (f32x2){eav[i], eav[i]};
                val01 += e2 * wlo[i];          // v_pk_fma_f32
                val23 += e2 * whi[i];
            }
            part01 += max0_2(val01);
            part23 += max0_2(val23);
        };

        int j = g;
        for (; j + 32 <= nch; j += 32) {
            ev(j); ev(j + 8); ev(j + 16); ev(j + 24);
        }
        for (; j < nch; j += 8)
            ev(j);
        __syncthreads();
    }

    float p = part01[0] * wg4.x + part01[1] * wg4.y + part23[0] * wg4.z + part23[1] * wg4.w;
    red[tid] = p;
    __syncthreads();
    for (int s = 128; s > 0; s >>= 1) {
        if (tid < s) red[tid] += red[tid + s];
        __syncthreads();
    }
    if (tid == 0) atomicAdd(acc, red[0]);
}

// ---------------- kernels ---------------------------------------------------
__global__ __launch_bounds__(256, 8) void fused_gm(
    const unsigned char* __restrict__ hs_in, const int* __restrict__ csr_src,
    const int* __restrict__ offs, const int* __restrict__ counts,
    const float* __restrict__ dinv, const float* __restrict__ bias,
    const unsigned short* __restrict__ Wt, int ncols, int uvcols,
    unsigned char* __restrict__ buv, unsigned char* __restrict__ bh, int n)
{
    __shared__ __align__(16) char smem[FUSED_LDS];
    fused_body(blockIdx.x, smem, hs_in, csr_src, offs, counts, dinv, bias,
               Wt, ncols, uvcols, buv, bh, n);
}

__global__ __launch_bounds__(256) void edge_mlp(
    const unsigned char* __restrict__ uv, const int* __restrict__ src,
    const int* __restrict__ dst, const float* __restrict__ ea,
    const float* __restrict__ We_e, const float* __restrict__ be,
    const float* __restrict__ Wg, float* __restrict__ acc, int E)
{
    __shared__ __align__(16) char smem[EDGE_LDS];
    edge_body(blockIdx.x, gridDim.x, smem, uv, src, dst, ea, We_e, be, Wg, acc, E);
}

// Co-dispatch: E(t) || Fa(t+1). Role assigned in chunks of 8 blocks so both
// roles round-robin all XCDs (parity would segregate roles onto XCD halves).
__global__ __launch_bounds__(256, 8) void fused_gm_edge(
    int nf,
    const unsigned char* __restrict__ hs_in, const int* __restrict__ csr_src,
    const int* __restrict__ offs, const int* __restrict__ counts,
    const float* __restrict__ dinv, const float* __restrict__ bias,
    const unsigned short* __restrict__ Wt, int ncols, int uvcols,
    unsigned char* __restrict__ buv, unsigned char* __restrict__ bh, int n,
    int ne,
    const unsigned char* __restrict__ uv, const int* __restrict__ src,
    const int* __restrict__ dst, const float* __restrict__ ea,
    const float* __restrict__ We_e, const float* __restrict__ be,
    const float* __restrict__ Wg, float* __restrict__ acc, int E)
{
    __shared__ __align__(16) char smem[EDGE_LDS];   // >= FUSED_LDS
    const int bid = blockIdx.x;
    const int nmin = (nf < ne) ? nf : ne;
    const int nch8 = nmin >> 3;           // full 8-chunks per role
    const int inter = nch8 * 16;          // interleaved region
    int role, idx;
    if (bid < inter) {
        int gg = bid >> 4, s = bid & 15;
        role = s >> 3;
        idx = gg * 8 + (s & 7);
    } else {
        int r = bid - inter;
        int fleft = nf - nch8 * 8;
        if (r < fleft) { role = 0; idx = nch8 * 8 + r; }
        else           { role = 1; idx = nch8 * 8 + (r - fleft); }
    }
    if (role == 0)
        fused_body(idx, smem, hs_in, csr_src, offs, counts, dinv, bias,
                   Wt, ncols, uvcols, buv, bh, n);
    else
        edge_body(idx, ne, smem, uv, src, dst, ea, We_e, be, Wg, acc, E);
}

// ---------------- CSR build ----------------
// rank[e] = arrival order among edges sharing dst (any bijection works).
__global__ void count_edges(const int* __restrict__ dst, int* __restrict__ counts,
                            int* __restrict__ rank, int E)
{
    int e = blockIdx.x * 256 + threadIdx.x;
    if (e < E) rank[e] = atomicAdd(&counts[dst[e]], 1);
}

__global__ void compute_dinv(const int* __restrict__ counts, float* __restrict__ dinv, int n)
{
    int i = blockIdx.x * 256 + threadIdx.x;
    if (i < n) dinv[i] = rsqrtf((float)counts[i] + 1.0f);
}

__global__ void scan1(const int* __restrict__ counts, int* __restrict__ scanned,
                      int* __restrict__ btot, int n)
{
    __shared__ int sh[256];
    int i = blockIdx.x * 256 + threadIdx.x;
    int v = (i < n) ? counts[i] : 0;
    sh[threadIdx.x] = v;
    __syncthreads();
    for (int off = 1; off < 256; off <<= 1) {
        int t = (threadIdx.x >= off) ? sh[threadIdx.x - off] : 0;
        __syncthreads();
        sh[threadIdx.x] += t;
        __syncthreads();
    }
    if (i < n) scanned[i] = sh[threadIdx.x] - v;  // exclusive
    if (threadIdx.x == 255) btot[blockIdx.x] = sh[255];
}

__global__ void scan2(int* __restrict__ btot, int nb)
{
    __shared__ int sh[256];
    int v = (threadIdx.x < nb) ? btot[threadIdx.x] : 0;
    sh[threadIdx.x] = v;
    __syncthreads();
    for (int off = 1; off < 256; off <<= 1) {
        int t = (threadIdx.x >= off) ? sh[threadIdx.x - off] : 0;
        __syncthreads();
        sh[threadIdx.x] += t;
        __syncthreads();
    }
    if (threadIdx.x < nb) btot[threadIdx.x] = sh[threadIdx.x] - v;  // exclusive
}

__global__ void scan3(const int* __restrict__ scanned, const int* __restrict__ btot,
                      int* __restrict__ offs, int n)
{
    int i = blockIdx.x * 256 + threadIdx.x;
    if (i < n) offs[i] = scanned[i] + btot[blockIdx.x];
}

// XCD-chunked fill: blocks with blockIdx%8==g write only dst in range g ->
// contiguous csr_src slice per XCD stays L2-resident, writeback ~3.2MB not
// 52MB. No atomics (rank precomputed). Heuristic is perf-only.
__global__ void fill_csr2(const int* __restrict__ src, const int* __restrict__ dst,
                          const int* __restrict__ rank, const int* __restrict__ offs,
                          int* __restrict__ csr_src, int E, int n)
{
    const int g8 = blockIdx.x & 7;
    const int b8 = blockIdx.x >> 3;
    const int nb8 = gridDim.x >> 3;
    const int chunk = (n + 7) >> 3;
    const int lo = g8 * chunk;
    const int hi = min(n, lo + chunk);
    for (int e = b8 * 256 + threadIdx.x; e < E; e += nb8 * 256) {
        int d = dst[e];
        if (d >= lo && d < hi)
            csr_src[offs[d] + rank[e]] = src[e];
    }
}

__global__ void write_out(const float* __restrict__ acc, const float* __restrict__ bg,
                          float* __restrict__ out, float invE, int T)
{
    int t = threadIdx.x;
    if (t < T) out[t] = acc[t] * invE + bg[0];
}

// ---------------------------------------------------------------------------

extern "C" void kernel_launch(void* const* d_in, const int* in_sizes, int n_in,
                              void* d_out, int out_size, void* d_ws, size_t ws_size,
                              hipStream_t stream)
{
    const float* x   = (const float*)d_in[0];
    const int*  eidx = (const int*)d_in[1];
    const float* ea  = (const float*)d_in[2];
    const float* W1  = (const float*)d_in[3];
    const float* b1  = (const float*)d_in[4];
    const float* W2  = (const float*)d_in[5];
    const float* b2  = (const float*)d_in[6];
    const float* W3  = (const float*)d_in[7];
    const float* b3  = (const float*)d_in[8];
    const float* We  = (const float*)d_in[9];
    const float* be  = (const float*)d_in[10];
    const float* Wg  = (const float*)d_in[11];
    const float* bg  = (const float*)d_in[12];

    const int N = in_sizes[0] / 128;
    const int E = in_sizes[1] / 2;
    const int T = in_sizes[2] / (E * 7);
    const int* src = eidx;
    const int* dst = eidx + E;

    char* wsp = (char*)d_ws;
    auto alloc = [&](size_t bytes) -> char* {
        char* p = wsp;
        wsp += (bytes + 255) / 256 * 256;
        return p;
    };
    int*   counts  = (int*)alloc((size_t)N * 4);
    int*   offs    = (int*)alloc((size_t)N * 4);
    int*   scanned = (int*)alloc((size_t)N * 4);
    int*   btot    = (int*)alloc(1024);
    int*   rank    = (int*)alloc((size_t)E * 4);
    int*   csr_src = (int*)alloc((size_t)E * 4);
    float* dinv    = (float*)alloc((size_t)N * 4);
    float* acc     = (float*)alloc(256);
    unsigned short* X0  = (unsigned short*)alloc((size_t)N * 128 * 2);  // x bf16
    unsigned char*  Bh0 = (unsigned char*)alloc((size_t)N * 128);       // hs fp8 (dbuf)
    unsigned char*  Bh1 = (unsigned char*)alloc((size_t)N * 128);
    unsigned char*  Buv = (unsigned char*)alloc((size_t)N * 256);       // uv fp8
    unsigned short* T1  = (unsigned short*)alloc(128 * 128 * 2);        // W^T bf16
    unsigned short* T2  = (unsigned short*)alloc(128 * 128 * 2);
    unsigned short* T3  = (unsigned short*)alloc(128 * 128 * 2);
    unsigned short* Tuv = (unsigned short*)alloc(384 * 128 * 2);        // [We_u|We_v|W2]^T

    hipMemsetAsync(counts, 0, (size_t)N * 4, stream);
    hipMemsetAsync(acc, 0, (size_t)T * 4, stream);

    to_bf16<<<(N * 128 / 4 + 255) / 256, 256, 0, stream>>>(x, X0, N * 128 / 4);
    transpose_w<<<dim3(8, 6), 256, 0, stream>>>(W1, W2, W3, We, T1, T2, T3, Tuv);

    count_edges<<<(E + 255) / 256, 256, 0, stream>>>(dst, counts, rank, E);
    compute_dinv<<<(N + 255) / 256, 256, 0, stream>>>(counts, dinv, N);
    const int nb = (N + 255) / 256;
    scan1<<<nb, 256, 0, stream>>>(counts, scanned, btot, N);
    scan2<<<1, 256, 0, stream>>>(btot, nb);
    scan3<<<nb, 256, 0, stream>>>(scanned, btot, offs, N);
    fill_csr2<<<2048, 256, 0, stream>>>(src, dst, rank, offs, csr_src, E, N);

    const int mmb = (N + 63) / 64;
    const int fgb = (N + GN - 1) / GN;
    const int emb = (E + EM_CHUNK - 1) / EM_CHUNK;

    unsigned char* hcur = Bh0;
    unsigned char* hnxt = Bh1;
    auto swap = [&]() { unsigned char* tmp = hcur; hcur = hnxt; hnxt = tmp; };

    // hs1 = (x @ W1) * dinv   (only timestep that uses W1)
    mfma_matmul<<<mmb, 256, 0, stream>>>(X0, T1, hcur, dinv, N);
    // Fa(0): x2 = relu(agg(hs1)*dinv + b1); hs2 = (x2 @ W2) * dinv
    fused_gm<<<fgb, 256, 0, stream>>>(hcur, csr_src, offs, counts, dinv, b1,
                                      T2, 128, 0, Buv, hnxt, N);
    swap();
    // Fb(0): hs3 = (relu(agg(hs2)*dinv + b2) @ W3) * dinv
    fused_gm<<<fgb, 256, 0, stream>>>(hcur, csr_src, offs, counts, dinv, b2,
                                      T3, 128, 0, Buv, hnxt, N);
    swap();

    for (int t = 0; t < T; ++t) {
        const bool last = (t == T - 1);
        // Fc(t): x3 = relu(agg(hs3)*dinv + b3); uv = x3 @ [We_u|We_v];
        // if not last, also hs1' = (x3 @ W2) * dinv   (W1:=W2 rebind)
        fused_gm<<<fgb, 256, 0, stream>>>(hcur, csr_src, offs, counts, dinv, b3,
                                          Tuv, last ? 256 : 384, 256, Buv, hnxt, N);
        if (last) {
            edge_mlp<<<emb, 256, 0, stream>>>(Buv, src, dst, ea + (size_t)t * E * 7,
                                              We + 256 * 128, be, Wg, acc + t, E);
        } else {
            swap();  // hcur = hs1'(t+1)
            // E(t)  ||  Fa(t+1): both depend only on Fc(t); co-dispatch.
            fused_gm_edge<<<fgb + emb, 256, 0, stream>>>(
                fgb, hcur, csr_src, offs, counts, dinv, b1, T2, 128, 0, Buv, hnxt, N,
                emb, Buv, src, dst, ea + (size_t)t * E * 7,
                We + 256 * 128, be, Wg, acc + t, E);
            swap();  // hcur = hs2(t+1)
            // Fb(t+1)
            fused_gm<<<fgb, 256, 0, stream>>>(hcur, csr_src, offs, counts, dinv, b2,
                                              T3, 128, 0, Buv, hnxt, N);
            swap();  // hcur = hs3(t+1)
        }
    }
    write_out<<<1, 64, 0, stream>>>(acc, bg, (float*)d_out, 1.0f / (float)E, T);
}